// Round 6
// baseline (235.160 us; speedup 1.0000x reference)
//
#include <hip/hip_runtime.h>
#include <math.h>

#define NPT 8192
#define HWIMG 19200
#define KCAP 128

using short8 = __attribute__((ext_vector_type(8))) short;
using short4v = __attribute__((ext_vector_type(4))) short;
using f32x4  = __attribute__((ext_vector_type(4))) float;
using f32x2  = __attribute__((ext_vector_type(2))) float;

__device__ __forceinline__ float lrelu(float x) { return x > 0.f ? x : 0.01f * x; }
__device__ __forceinline__ unsigned short f2bf(float v) {
  unsigned u = __float_as_uint(v);
  return (unsigned short)((u + 0x7fffu + ((u >> 16) & 1u)) >> 16);
}
__device__ __forceinline__ float bf2f(unsigned short h) {
  return __uint_as_float(((unsigned)h) << 16);
}
__device__ __forceinline__ void split2(float v, unsigned short& h, unsigned short& l) {
  h = f2bf(v);
  l = f2bf(v - bf2f(h));
}
__device__ __forceinline__ void mfma3(f32x4& acc, short8 ah, short8 al, short8 wh, short8 wl) {
  acc = __builtin_amdgcn_mfma_f32_16x16x32_bf16(ah, wh, acc, 0, 0, 0);
  acc = __builtin_amdgcn_mfma_f32_16x16x32_bf16(al, wh, acc, 0, 0, 0);
  acc = __builtin_amdgcn_mfma_f32_16x16x32_bf16(ah, wl, acc, 0, 0, 0);
}

// fragment-sequential swizzle: element (row o, k) of a [N,K] matrix lives at
// chunk ((o/16)*Kc + k/32)*64 + (k/8)%4*16 + o%16, byte-offset k%8.
__device__ __forceinline__ int swz(int o, int k, int Kc) {
  return ((((o >> 4) * Kc + (k >> 5)) << 6) + (((k >> 3) & 3) << 4) + (o & 15)) * 8 + (k & 7);
}

// weight-plane segment offsets (in shorts)
#define OFF_PCONV2  0
#define OFF_CONV1   8192
#define OFF_CONV2   10240
#define OFF_PSCONV1 18432
#define OFF_PSCONV2 51200
#define OFF_FINAL   83968
#define OFF_W3      137216
#define OFF_W2P     186368

// ---------------- prep: everything input-only (c4, feat, weights, biases) ------
#define S_C4    NPT
#define S_G     129
#define S_BIASC 128
#define S_B2C   64
#define S_FEAT  (NPT*32)
#define S_W3    49152
#define S_W2P   8192
#define S_WSPL  OFF_W3
#define PREP_TOTAL (S_C4 + S_G + S_BIASC + S_B2C + S_FEAT + S_W3 + S_W2P + S_WSPL)
__global__ void k_prep(const float* __restrict__ cloud, const int* __restrict__ choose,
                       const float* __restrict__ img,
                       const float* __restrict__ seg1_w, const float* __restrict__ dis1_w,
                       const float* __restrict__ seg1_b, const float* __restrict__ dis1_b,
                       const float* __restrict__ seg2_w, const float* __restrict__ dis2_w,
                       const float* __restrict__ seg2_b, const float* __restrict__ dis2_b,
                       const float* __restrict__ pconv2_w, const float* __restrict__ conv1_w,
                       const float* __restrict__ conv2_w, const float* __restrict__ psconv1_w,
                       const float* __restrict__ psconv2_w, const float* __restrict__ final_w,
                       float* __restrict__ c4, float* __restrict__ soa,
                       float* __restrict__ g,
                       float* __restrict__ biasc, float* __restrict__ bias2c,
                       float* __restrict__ feat,
                       unsigned short* __restrict__ feat_h, unsigned short* __restrict__ feat_l,
                       unsigned short* __restrict__ Wh, unsigned short* __restrict__ Wl) {
  int j = blockIdx.x * blockDim.x + threadIdx.x;
  if (j < S_C4) {
    float x = cloud[j*3+0], y = cloud[j*3+1], z = cloud[j*3+2];
    float4 v; v.x = x; v.y = y; v.z = z; v.w = x*x + y*y + z*z;
    ((float4*)c4)[j] = v;
    soa[j] = x; soa[NPT + j] = y; soa[2*NPT + j] = z; soa[3*NPT + j] = v.w;
    return;
  }
  j -= S_C4;
  if (j < S_G) { g[j] = 0.f; return; }
  j -= S_G;
  if (j < S_BIASC) { biasc[j] = (j < 64) ? seg1_b[j] : dis1_b[j-64]; return; }
  j -= S_BIASC;
  if (j < S_B2C) { bias2c[j] = (j < 32) ? seg2_b[j] : dis2_b[j-32]; return; }
  j -= S_B2C;
  if (j < S_FEAT) {
    int n = j >> 5, ch = j & 31;
    float v = img[ch*HWIMG + choose[n]];
    feat[j] = v;
    unsigned short hh, ll; split2(v, hh, ll);
    int d = swz(n, ch, 1);
    feat_h[d] = hh; feat_l[d] = ll;
    return;
  }
  j -= S_FEAT;
  if (j < S_W3) {                          // conv3 weight transpose + split
    int h = j / 24576, r = j - h*24576, o = r / 384, k = r - o*384;
    int t = k >> 7, c = k & 127;
    float v = (h ? dis1_w : seg1_w)[o*384 + c*3 + t];
    unsigned short hh, ll; split2(v, hh, ll);
    int d = OFF_W3 + swz(h*64 + o, k, 12);
    Wh[d] = hh; Wl[d] = ll;
    return;
  }
  j -= S_W3;
  if (j < S_W2P) {                         // W2p block-diagonal + split
    int o = j >> 7, c = j & 127;
    float v = 0.f;
    if (o < 32) { if (c < 64) v = seg2_w[o*64 + c]; }
    else        { if (c >= 64) v = dis2_w[(o-32)*64 + (c-64)]; }
    unsigned short hh, ll; split2(v, hh, ll);
    int d = OFF_W2P + swz(o, c, 4);
    Wh[d] = hh; Wl[d] = ll;
    return;
  }
  j -= S_W2P;
  if (j < S_WSPL) {                        // weight split (swizzled)
    float v; int d;
    if (j < OFF_CONV1) {
      int o = j >> 6, k = j & 63;
      v = pconv2_w[j]; d = OFF_PCONV2 + swz(o, k, 2);
    } else if (j < OFF_CONV2) {
      int jj = j - OFF_CONV1, o = jj >> 5, k = jj & 31;
      v = conv1_w[jj]; d = OFF_CONV1 + swz(o, k, 1);
    } else if (j < OFF_PSCONV1) {
      int jj = j - OFF_CONV2, o = jj >> 6, k = jj & 63;
      v = conv2_w[jj]; d = OFF_CONV2 + swz(o, k, 2);
    } else if (j < OFF_PSCONV2) {
      int jj = j - OFF_PSCONV1, o = jj >> 7, k = jj & 127;
      v = psconv1_w[jj]; d = OFF_PSCONV1 + swz(o, k, 4);
    } else if (j < OFF_FINAL) {
      int jj = j - OFF_PSCONV2, o = jj >> 8, k = jj & 255;
      v = psconv2_w[jj]; d = OFF_PSCONV2 + swz(o, k, 8);
    } else {
      int jj = j - OFF_FINAL, o = jj / 416, k = jj - o*416;
      v = final_w[jj]; d = OFF_FINAL + swz(o, k, 13);
    }
    unsigned short hh, ll; split2(v, hh, ll);
    Wh[d] = hh; Wl[d] = ll;
  }
}

// ---------------- bitonic helpers ---------------------------------------------
__device__ __forceinline__ unsigned bsort32u(unsigned key, int lane) {
#pragma unroll
  for (int k = 2; k <= 64; k <<= 1) {
#pragma unroll
    for (int j = k >> 1; j > 0; j >>= 1) {
      unsigned o = __shfl_xor(key, j, 64);
      bool keepmin = (((lane & j) == 0) == ((lane & k) == 0));
      key = ((o < key) == keepmin) ? o : key;
    }
  }
  return key;
}
__device__ __forceinline__ unsigned long long bsort64(unsigned long long key, int lane) {
#pragma unroll
  for (int k = 2; k <= 64; k <<= 1) {
#pragma unroll
    for (int j = k >> 1; j > 0; j >>= 1) {
      unsigned long long o = __shfl_xor(key, j, 64);
      bool keepmin = (((lane & j) == 0) == ((lane & k) == 0));
      bool omin = o < key;
      key = (omin == keepmin) ? o : key;
    }
  }
  return key;
}
__device__ __forceinline__ unsigned long long bmerge64(unsigned long long key, int lane) {
#pragma unroll
  for (int j = 32; j > 0; j >>= 1) {
    unsigned long long o = __shfl_xor(key, j, 64);
    bool keepmin = ((lane & j) == 0);
    bool omin = o < key;
    key = (omin == keepmin) ? o : key;
  }
  return key;
}

// ---------------- mega: knn (0..1023, 8 q/blk) | dc (1024) | chains (1025..2048)
// LDS: knn needs 8256 B (smin overlaid with sd/sj), chain needs 16384 B
#define MEGA_GRID 2049
__global__ __launch_bounds__(256) void k_mega(const float4* __restrict__ c4,
                                              const float* __restrict__ soa,
                                              int* __restrict__ idxo, float* __restrict__ wo,
                                              const float* __restrict__ cloud,
                                              const float* __restrict__ tvec,
                                              float* __restrict__ dc,
                                              const float* __restrict__ pconv1_w, const float* __restrict__ pconv1_b,
                                              const float* __restrict__ pconv2_b, const float* __restrict__ psconv1_b,
                                              const float* __restrict__ psconv2_b,
                                              const unsigned short* __restrict__ feat_h,
                                              const unsigned short* __restrict__ feat_l,
                                              const float* __restrict__ conv1_b, const float* __restrict__ conv2_b,
                                              const unsigned short* __restrict__ Wh,
                                              const unsigned short* __restrict__ Wl,
                                              float* __restrict__ pf, float* __restrict__ Yfp,
                                              float* __restrict__ Yf) {
  __shared__ __align__(16) char smem[16384];
  int tid = threadIdx.x, lane = tid & 63, w = tid >> 6;
  int mr = lane & 15, q = lane >> 4;
  if (blockIdx.x > 1024) {
    unsigned short* sh_h = (unsigned short*)smem;            // [0,4096) shorts: A @0..2048, B @2048..4096
    unsigned short* sh_l = (unsigned short*)(smem + 8192);
    int cb = blockIdx.x - 1025;
    if (cb < 512) {
      int m0 = cb * 16;
      // stage 1: pconv1 (K=3) directly in A-frag ownership
      float4 cp = c4[m0 + mr];
      short8 ah0, al0, ah1, al1;
#pragma unroll
      for (int j = 0; j < 8; ++j) {
        int c0 = q*8 + j, c1 = 32 + q*8 + j;
        float v0 = lrelu(fmaf(cp.x, pconv1_w[c0*3+0], fmaf(cp.y, pconv1_w[c0*3+1],
                          fmaf(cp.z, pconv1_w[c0*3+2], pconv1_b[c0]))));
        float v1 = lrelu(fmaf(cp.x, pconv1_w[c1*3+0], fmaf(cp.y, pconv1_w[c1*3+1],
                          fmaf(cp.z, pconv1_w[c1*3+2], pconv1_b[c1]))));
        unsigned short hh, ll;
        split2(v0, hh, ll); ah0[j] = (short)hh; al0[j] = (short)ll;
        split2(v1, hh, ll); ah1[j] = (short)hh; al1[j] = (short)ll;
      }
      // stage 2: pconv2 (K=64, N=128) -> region A
      f32x4 acc[2];
#pragma unroll
      for (int t = 0; t < 2; ++t) { f32x4 z = {0.f,0.f,0.f,0.f}; acc[t] = z; }
      const unsigned short* W2h = Wh + OFF_PCONV2;
      const unsigned short* W2l = Wl + OFF_PCONV2;
#pragma unroll
      for (int tt = 0; tt < 2; ++tt) {
        int t1 = 2*w + tt;
        int w0 = ((t1*2 + 0)*64 + lane)*8, w1 = ((t1*2 + 1)*64 + lane)*8;
        mfma3(acc[tt], ah0, al0, *(const short8*)(W2h + w0), *(const short8*)(W2l + w0));
        mfma3(acc[tt], ah1, al1, *(const short8*)(W2h + w1), *(const short8*)(W2l + w1));
      }
#pragma unroll
      for (int tt = 0; tt < 2; ++tt) {
        int t1 = 2*w + tt, n = t1*16 + mr;
        float b = pconv2_b[n];
        int ks2 = t1 >> 1, q2 = (t1 & 1)*2 + (mr >> 3), jd = mr & 7;
#pragma unroll
        for (int r = 0; r < 4; ++r) {
          int row = q*4 + r;
          float v = acc[tt][r] + b;
          pf[(size_t)(m0+row)*128 + n] = v;
          unsigned short hh, ll; split2(v, hh, ll);
          int p = ((ks2*16 + row)*4 + q2)*8 + jd;
          sh_h[p] = hh; sh_l[p] = ll;
        }
      }
      __syncthreads();
      // stages 3+4: psconv1/psconv2 in two 128-col halves (acc3 persists)
      f32x4 acc3[2];
#pragma unroll
      for (int t = 0; t < 2; ++t) { f32x4 z = {0.f,0.f,0.f,0.f}; acc3[t] = z; }
      const unsigned short* W3h = Wh + OFF_PSCONV1;
      const unsigned short* W3l = Wl + OFF_PSCONV1;
      const unsigned short* W4h = Wh + OFF_PSCONV2;
      const unsigned short* W4l = Wl + OFF_PSCONV2;
#pragma unroll
      for (int h = 0; h < 2; ++h) {
        f32x4 acc2[2];
#pragma unroll
        for (int t = 0; t < 2; ++t) { f32x4 z = {0.f,0.f,0.f,0.f}; acc2[t] = z; }
#pragma unroll
        for (int ks = 0; ks < 4; ++ks) {
          int ap = ((ks*16 + mr)*4 + q)*8;
          short8 ah = *(const short8*)&sh_h[ap];
          short8 al = *(const short8*)&sh_l[ap];
#pragma unroll
          for (int tt = 0; tt < 2; ++tt) {
            int ts = h*8 + 2*w + tt;
            int wb = ((ts*4 + ks)*64 + lane)*8;
            mfma3(acc2[tt], ah, al, *(const short8*)(W3h + wb), *(const short8*)(W3l + wb));
          }
        }
#pragma unroll
        for (int tt = 0; tt < 2; ++tt) {
          int tl = 2*w + tt;
          int n = h*128 + tl*16 + mr;
          float b = psconv1_b[n];
          int ks3 = tl >> 1, q3 = (tl & 1)*2 + (mr >> 3), jd = mr & 7;
#pragma unroll
          for (int r = 0; r < 4; ++r) {
            int row = q*4 + r;
            float v = lrelu(acc2[tt][r] + b);
            unsigned short hh, ll; split2(v, hh, ll);
            int p = 2048 + ((ks3*16 + row)*4 + q3)*8 + jd;
            sh_h[p] = hh; sh_l[p] = ll;
          }
        }
        __syncthreads();
#pragma unroll
        for (int ks = 0; ks < 4; ++ks) {
          int ap = 2048 + ((ks*16 + mr)*4 + q)*8;
          short8 ah = *(const short8*)&sh_h[ap];
          short8 al = *(const short8*)&sh_l[ap];
#pragma unroll
          for (int tt = 0; tt < 2; ++tt) {
            int wb = (((2*w+tt)*8 + h*4 + ks)*64 + lane)*8;
            mfma3(acc3[tt], ah, al, *(const short8*)(W4h + wb), *(const short8*)(W4l + wb));
          }
        }
        __syncthreads();
      }
#pragma unroll
      for (int tt = 0; tt < 2; ++tt) {
        int n = (2*w+tt)*16 + mr;
        float b = psconv2_b[n];
#pragma unroll
        for (int r = 0; r < 4; ++r)
          Yfp[(size_t)(m0 + q*4 + r)*128 + n] = acc3[tt][r] + b;
      }
    } else {
      int m0 = (cb - 512) * 16;
      int ab = ((m0 >> 4)*64 + lane)*8;
      short8 ah = *(const short8*)(feat_h + ab);
      short8 al = *(const short8*)(feat_l + ab);
      f32x4 acc = {0.f,0.f,0.f,0.f};
      const unsigned short* W1h = Wh + OFF_CONV1;
      const unsigned short* W1l = Wl + OFF_CONV1;
      {
        int wb = (w*64 + lane)*8;
        mfma3(acc, ah, al, *(const short8*)(W1h + wb), *(const short8*)(W1l + wb));
      }
      {
        int n = w*16 + mr;
        float b = conv1_b[n];
        int ks2 = n >> 5, q2 = (n >> 3) & 3, jd = mr & 7;
#pragma unroll
        for (int r = 0; r < 4; ++r) {
          int row = q*4 + r;
          float v = lrelu(acc[r] + b);
          unsigned short hh, ll; split2(v, hh, ll);
          int p = ((ks2*16 + row)*4 + q2)*8 + jd;
          sh_h[p] = hh; sh_l[p] = ll;
        }
      }
      __syncthreads();
      f32x4 acc2[2];
#pragma unroll
      for (int t = 0; t < 2; ++t) { f32x4 z = {0.f,0.f,0.f,0.f}; acc2[t] = z; }
      const unsigned short* W2h = Wh + OFF_CONV2;
      const unsigned short* W2l = Wl + OFF_CONV2;
#pragma unroll
      for (int ks = 0; ks < 2; ++ks) {
        int ap = ((ks*16 + mr)*4 + q)*8;
        short8 a2 = *(const short8*)&sh_h[ap];
        short8 a2l = *(const short8*)&sh_l[ap];
#pragma unroll
        for (int tt = 0; tt < 2; ++tt) {
          int wb = (((2*w+tt)*2 + ks)*64 + lane)*8;
          mfma3(acc2[tt], a2, a2l, *(const short8*)(W2h + wb), *(const short8*)(W2l + wb));
        }
      }
#pragma unroll
      for (int tt = 0; tt < 2; ++tt) {
        int n = (2*w+tt)*16 + mr;
        float b = conv2_b[n];
#pragma unroll
        for (int r = 0; r < 4; ++r)
          Yf[(size_t)(m0 + q*4 + r)*128 + n] = acc2[tt][r] + b;
      }
    }
    return;
  }
  if (blockIdx.x == 1024) {
    float* sred = (float*)smem;
    float tx = tvec[0], ty = tvec[1], tz = tvec[2];
    float v[32];
    float m = -INFINITY;
#pragma unroll
    for (int i2 = 0; i2 < 32; ++i2) {
      int n = i2*256 + tid;
      float ax = cloud[n*3+0] + tx, ay = cloud[n*3+1] + ty, az = cloud[n*3+2] + tz;
      v[i2] = sqrtf(ax*ax + ay*ay + az*az);
      m = fmaxf(m, v[i2]);
    }
#pragma unroll
    for (int o = 1; o < 64; o <<= 1) m = fmaxf(m, __shfl_xor(m, o, 64));
    if (lane == 0) sred[w] = m;
    __syncthreads();
    m = fmaxf(fmaxf(sred[0], sred[1]), fmaxf(sred[2], sred[3]));
    __syncthreads();
    float s = 0.f;
#pragma unroll
    for (int i2 = 0; i2 < 32; ++i2) { v[i2] = expf(v[i2] - m); s += v[i2]; }
#pragma unroll
    for (int o = 1; o < 64; o <<= 1) s += __shfl_xor(s, o, 64);
    if (lane == 0) sred[w] = s;
    __syncthreads();
    s = sred[0] + sred[1] + sred[2] + sred[3];
#pragma unroll
    for (int i2 = 0; i2 < 32; ++i2) dc[i2*256 + tid] = v[i2] / s;
    return;
  }
  // knn: 8 queries/block, SoA packed-fp32 scan. smin (pass 1) overlays sd/sj
  // (pass 2) -- disjoint in time, barrier-separated.
  float (*smin)[256] = (float(*)[256])smem;                 // 8192 B (pass 1)
  float (*sd)[KCAP] = (float(*)[KCAP])smem;                 // 4096 B (pass 2)
  int   (*sj)[KCAP] = (int(*)[KCAP])(smem + 4096);          // 4096 B (pass 2)
  float* sTv = (float*)(smem + 8192);                       // 32 B
  int*   scnt = (int*)(smem + 8224);                        // 32 B
  const float* cx = soa;
  const float* cy = soa + NPT;
  const float* cz = soa + 2*NPT;
  const float* cw = soa + 3*NPT;
  int q0 = blockIdx.x * 8;
  float4 P[8];
#pragma unroll
  for (int i = 0; i < 8; ++i) P[i] = c4[q0 + i];
  f32x2 QX[8], QY[8], QZ[8], QW[8];
#pragma unroll
  for (int i = 0; i < 8; ++i) {
    QX[i][0] = QX[i][1] = -2.f*P[i].x;
    QY[i][0] = QY[i][1] = -2.f*P[i].y;
    QZ[i][0] = QZ[i][1] = -2.f*P[i].z;
    QW[i][0] = QW[i][1] = P[i].w;
  }
#define PDOT(QXI,QYI,QZI,QWI) \
  __builtin_elementwise_fma(X, QXI, __builtin_elementwise_fma(Yv, QYI, \
    __builtin_elementwise_fma(Z, QZI, Wv + QWI)))
  f32x2 inf2 = {INFINITY, INFINITY};
  f32x2 mv[8];
#pragma unroll
  for (int i = 0; i < 8; ++i) mv[i] = inf2;
  for (int t = 0; t < 16; ++t) {
    int j = t*512 + tid*2;
    f32x2 X  = *(const f32x2*)&cx[j];
    f32x2 Yv = *(const f32x2*)&cy[j];
    f32x2 Z  = *(const f32x2*)&cz[j];
    f32x2 Wv = *(const f32x2*)&cw[j];
#pragma unroll
    for (int i = 0; i < 8; ++i)
      mv[i] = __builtin_elementwise_min(mv[i], PDOT(QX[i],QY[i],QZ[i],QW[i]));
  }
#pragma unroll
  for (int i = 0; i < 8; ++i) smin[i][tid] = fminf(mv[i][0], mv[i][1]);
  if (tid < 8) scnt[tid] = 0;
  __syncthreads();
#pragma unroll
  for (int u = 0; u < 2; ++u) {
    int qq = w*2 + u;
    float4 vv = *(const float4*)&smin[qq][lane*4];
    float m4 = fmaxf(fminf(fminf(vv.x, vv.y), fminf(vv.z, vv.w)), 0.f);
    unsigned key = bsort32u(__float_as_uint(m4), lane);
    float T = __uint_as_float(__shfl(key, 31, 64));
    if (lane == 0) sTv[qq] = T * (1.f + 2e-5f) + 4e-5f;
  }
  __syncthreads();   // smin reads done; sd/sj overlay now writable
  float Tq[8];
#pragma unroll
  for (int i = 0; i < 8; ++i) Tq[i] = sTv[i];
#define APPEND8(Q, PQ, XX, YY, ZZ, J) { \
    float dx_ = (PQ).x-(XX), dy_ = (PQ).y-(YY), dz_ = (PQ).z-(ZZ); \
    float de_ = dx_*dx_ + dy_*dy_ + dz_*dz_; \
    int p_ = atomicAdd(&scnt[Q],1); if (p_ < KCAP) { sd[Q][p_] = de_; sj[Q][p_] = (J); } }
  for (int t = 0; t < 16; ++t) {
    int j = t*512 + tid*2;
    f32x2 X  = *(const f32x2*)&cx[j];
    f32x2 Yv = *(const f32x2*)&cy[j];
    f32x2 Z  = *(const f32x2*)&cz[j];
    f32x2 Wv = *(const f32x2*)&cw[j];
#pragma unroll
    for (int i = 0; i < 8; ++i) {
      f32x2 d = PDOT(QX[i],QY[i],QZ[i],QW[i]);
      if (d[0] <= Tq[i]) APPEND8(i, P[i], X[0], Yv[0], Z[0], j);
      if (d[1] <= Tq[i]) APPEND8(i, P[i], X[1], Yv[1], Z[1], j+1);
    }
  }
  __syncthreads();
#pragma unroll
  for (int u = 0; u < 2; ++u) {
    int qq = w*2 + u;
    int M = scnt[qq]; if (M > KCAP) M = KCAP;
    unsigned long long key = (lane < M)
        ? (((unsigned long long)__float_as_uint(sd[qq][lane]) << 32) | (unsigned)sj[qq][lane])
        : ~0ull;
    key = bsort64(key, lane);
    for (int base = 64; base < M; base += 64) {
      unsigned long long nk = (base + lane < M)
          ? (((unsigned long long)__float_as_uint(sd[qq][base+lane]) << 32) | (unsigned)sj[qq][base+lane])
          : ~0ull;
      nk = bsort64(nk, lane);
      nk = __shfl_xor(nk, 63, 64);
      key = key < nk ? key : nk;
      key = bmerge64(key, lane);
    }
    float dsel = __uint_as_float((unsigned)(key >> 32));
    int   jsel = (int)(unsigned)(key & 0xffffffffu);
    float v = -sqrtf(dsel);
    float mx = v;
#pragma unroll
    for (int o = 1; o < 32; o <<= 1) mx = fmaxf(mx, __shfl_xor(mx, o, 64));
    float e = expf(v - mx);
    float s = e;
#pragma unroll
    for (int o = 1; o < 32; o <<= 1) s += __shfl_xor(s, o, 64);
    if (lane < 32) {
      int qd = q0 + qq;
      wo[qd*32 + lane] = e / s;
      idxo[qd*32 + lane] = jsel;
    }
  }
}

// ---------------- tail: pool(18 rows) + final GEMM + conv3 + head + g-partials -
// NOW 512 threads (8 waves): grid 512 caps blocks at 2/CU (LDS 42.5KB -> 3 max),
// so waves/CU was 8 -- the latency-bound gather's limiter. 8 waves/block doubles
// outstanding loads per CU. MFMA phases: each warp owns ONE 16-col n-tile
// (t1 = w), total MFMA unchanged. P3c/P5 keep 256/64-thread shapes via guards.
__global__ __launch_bounds__(512) void k_tail(const float* __restrict__ Yf,
                                              const float* __restrict__ Yfp,
                                              const float* __restrict__ feat,
                                              const float* __restrict__ pf,
                                              const int* __restrict__ idx,
                                              const float* __restrict__ wsm,
                                              const unsigned short* __restrict__ Wh,
                                              const unsigned short* __restrict__ Wl,
                                              const float* __restrict__ final_b,
                                              const float* __restrict__ biasc,
                                              const float* __restrict__ bias2c,
                                              const float* __restrict__ segw, const float* __restrict__ segb,
                                              const float* __restrict__ disw, const float* __restrict__ disb,
                                              const float* __restrict__ dcw, const float* __restrict__ segin,
                                              float* __restrict__ g,
                                              float* __restrict__ osegp, float* __restrict__ odisp) {
  __shared__ int sjn[18][32];
  __shared__ float swn[18][32];
  __shared__ __align__(16) char sbuf[37440];
  int tid = threadIdx.x, lane = tid & 63, w = tid >> 6;
  int mr = lane & 15, q = lane >> 4;
  int mt = blockIdx.x, m0 = mt * 16;
  // P1: neighbor lists for 18 rows (halo +-1)
  for (int t = tid; t < 18*32; t += 512) {
    int lr = t >> 5, k = t & 31, gr = m0 - 1 + lr;
    if (gr >= 0 && gr < NPT) { sjn[lr][k] = idx[gr*32+k]; swn[lr][k] = wsm[gr*32+k]; }
    else { sjn[lr][k] = 0; swn[lr][k] = 0.f; }
  }
  __syncthreads();
  // P2: build fin[18][416] split planes in LDS (1872 items of 4 channels).
  // Load-all-then-reduce batch; 512 threads halve per-thread items -> 2x the
  // concurrent gather streams per CU.
  for (int t = tid; t < 1872; t += 512) {
    int lr, col;
    float4 v4;
    if (t < 1152) {
      lr = t >> 6; int arr = (t >> 5) & 1, cg = t & 31;
      const float* Y = arr ? Yf : Yfp;
      float4 vv[32];
#pragma unroll
      for (int k = 0; k < 32; ++k)
        vv[k] = *(const float4*)&Y[(size_t)sjn[lr][k]*128 + cg*4];
      float ax = -INFINITY, ay = -INFINITY, az = -INFINITY, aw = -INFINITY;
#pragma unroll
      for (int k = 0; k < 32; ++k) {
        float wk = swn[lr][k];
        ax = fmaxf(ax, wk*vv[k].x); ay = fmaxf(ay, wk*vv[k].y);
        az = fmaxf(az, wk*vv[k].z); aw = fmaxf(aw, wk*vv[k].w);
      }
      v4.x = lrelu(ax); v4.y = lrelu(ay); v4.z = lrelu(az); v4.w = lrelu(aw);
      col = (arr ? 160 : 0) + cg*4;
    } else if (t < 1728) {
      int u = t - 1152; lr = u >> 5; int cg = u & 31;
      int gr = m0 - 1 + lr;
      int gc = gr < 0 ? 0 : (gr >= NPT ? NPT-1 : gr);
      float4 p4 = *(const float4*)&pf[(size_t)gc*128 + cg*4];
      v4.x = lrelu(p4.x); v4.y = lrelu(p4.y); v4.z = lrelu(p4.z); v4.w = lrelu(p4.w);
      col = 288 + cg*4;
    } else {
      int u = t - 1728; lr = u >> 3; int cg = u & 7;
      int gr = m0 - 1 + lr;
      int gc = gr < 0 ? 0 : (gr >= NPT ? NPT-1 : gr);
      float4 p4 = *(const float4*)&feat[(size_t)gc*32 + cg*4];
      v4.x = lrelu(p4.x); v4.y = lrelu(p4.y); v4.z = lrelu(p4.z); v4.w = lrelu(p4.w);
      col = 128 + cg*4;
    }
    int gr = m0 - 1 + lr;
    if (gr < 0 || gr >= NPT) { v4.x = 0.f; v4.y = 0.f; v4.z = 0.f; v4.w = 0.f; }
    int ks = col >> 5, qq = (col >> 3) & 3, j0 = col & 7;
    char* base = sbuf + (ks*18 + lr)*80 + qq*16 + j0*2;
    short4v hv, lv;
    unsigned short hh, ll;
    split2(v4.x, hh, ll); hv[0] = (short)hh; lv[0] = (short)ll;
    split2(v4.y, hh, ll); hv[1] = (short)hh; lv[1] = (short)ll;
    split2(v4.z, hh, ll); hv[2] = (short)hh; lv[2] = (short)ll;
    split2(v4.w, hh, ll); hv[3] = (short)hh; lv[3] = (short)ll;
    *(short4v*)base = hv;
    *(short4v*)(base + 18720) = lv;
  }
  __syncthreads();
  // P3: final GEMM (K=416); warp w owns n-tile w (16 cols), rows 0..15 (A) and
  // 16..17 clamp (B)
  f32x4 accA = {0.f,0.f,0.f,0.f}, accB = {0.f,0.f,0.f,0.f};
  const unsigned short* WFh = Wh + OFF_FINAL;
  const unsigned short* WFl = Wl + OFF_FINAL;
#pragma unroll
  for (int ks = 0; ks < 13; ++ks) {
    int arB = 16 + mr; if (arB > 17) arB = 17;
    const char* pA = sbuf + (ks*18 + mr)*80 + q*16;
    const char* pB = sbuf + (ks*18 + arB)*80 + q*16;
    short8 ahA = *(const short8*)pA;
    short8 alA = *(const short8*)(pA + 18720);
    short8 ahB = *(const short8*)pB;
    short8 alB = *(const short8*)(pB + 18720);
    int wb = ((w*13 + ks)*64 + lane)*8;
    short8 wh = *(const short8*)(WFh + wb);
    short8 wl = *(const short8*)(WFl + wb);
    mfma3(accA, ahA, alA, wh, wl);
    mfma3(accB, ahB, alB, wh, wl);
  }
  __syncthreads();   // all fin reads done; overlay region now writable
  // P3b: write fused split planes to LDS overlay (zero OOB rows = conv zero-pad)
  {
    int t2 = w, n = t2*16 + mr;
    float b = final_b[n];
    int ksA = t2 >> 1, qq = (t2 & 1)*2 + (mr >> 3), jd = mr & 7;
#pragma unroll
    for (int r = 0; r < 4; ++r) {            // rows 0..15 (tile A)
      int lr = q*4 + r;
      int gr = m0 - 1 + lr;
      float v = accA[r] + b;
      if (gr < 0 || gr >= NPT) v = 0.f;
      unsigned short hh, ll; split2(v, hh, ll);
      char* p = sbuf + (ksA*18 + lr)*80 + qq*16 + jd*2;
      *(unsigned short*)p = hh;
      *(unsigned short*)(p + 5760) = ll;
    }
#pragma unroll
    for (int r = 0; r < 4; ++r) {            // rows 16..17 (tile B, clamped)
      int lr = 16 + q*4 + r;
      if (lr > 17) continue;
      int gr = m0 - 1 + lr;
      float v = accB[r] + b;
      if (gr < 0 || gr >= NPT) v = 0.f;
      unsigned short hh, ll; split2(v, hh, ll);
      char* p = sbuf + (ksA*18 + lr)*80 + qq*16 + jd*2;
      *(unsigned short*)p = hh;
      *(unsigned short*)(p + 5760) = ll;
    }
  }
  __syncthreads();
  // P3c: per-block weighted partial g -> fire-and-forget atomicAdd (no fence)
  if (tid < 256) {
    int ks2 = tid >> 6, q2 = (tid >> 4) & 3, mr2 = tid & 15;
    int lr = mr2 + 1;
    const char* p = sbuf + (ks2*18 + lr)*80 + q2*16;
    short8 oh = *(const short8*)p;
    short8 ol = *(const short8*)(p + 5760);
    int gr = m0 + mr2;
    float wrow = dcw[gr] * segin[gr];
    float* sred = (float*)(sbuf + 26112);
#pragma unroll
    for (int j = 0; j < 8; ++j)
      sred[tid*8 + j] = (bf2f((unsigned short)oh[j]) + bf2f((unsigned short)ol[j])) * wrow;
  }
  __syncthreads();
  if (tid < 128) {
    float* sred = (float*)(sbuf + 26112);
    int ks = tid >> 5, q2 = (tid >> 3) & 3, j = tid & 7;
    float s = 0.f;
#pragma unroll
    for (int mr2 = 0; mr2 < 16; ++mr2) s += sred[((ks << 6) + (q2 << 4) + mr2)*8 + j];
    atomicAdd(&g[tid], s);
  }
  // P4: conv3 (K=384 via taps); warp w owns n-tile w
  f32x4 acc3 = {0.f,0.f,0.f,0.f};
  const unsigned short* W3h = Wh + OFF_W3;
  const unsigned short* W3l = Wl + OFF_W3;
#pragma unroll
  for (int ks = 0; ks < 12; ++ks) {
    int tap = ks >> 2, ksA = ks & 3;
    int ar = mr + tap;                     // local fused row 0..17
    const char* p = sbuf + (ksA*18 + ar)*80 + q*16;
    short8 ah = *(const short8*)p;
    short8 al = *(const short8*)(p + 5760);
    int wb = ((w*12 + ks)*64 + lane)*8;
    mfma3(acc3, ah, al, *(const short8*)(W3h + wb), *(const short8*)(W3l + wb));
  }
  {
    int t2 = w, n = t2*16 + mr;
    float b = biasc[n];
    int ks2 = t2 >> 1, q2 = (t2 & 1)*2 + (mr >> 3), jd = mr & 7;
#pragma unroll
    for (int r = 0; r < 4; ++r) {
      int row = q*4 + r;
      float v = lrelu(acc3[r] + b);
      unsigned short hh, ll; split2(v, hh, ll);
      char* p = sbuf + 11520 + (ks2*16 + row)*80 + q2*16 + jd*2;
      *(unsigned short*)p = hh;
      *(unsigned short*)(p + 5120) = ll;
    }
  }
  __syncthreads();
  // P5: head GEMM (K=128, block-diag seg2|dis2) on warps 0..3 only
  if (w < 4) {
    f32x4 acc4 = {0.f,0.f,0.f,0.f};
    const unsigned short* WPh = Wh + OFF_W2P;
    const unsigned short* WPl = Wl + OFF_W2P;
#pragma unroll
    for (int ks = 0; ks < 4; ++ks) {
      const char* p = sbuf + 11520 + (ks*16 + mr)*80 + q*16;
      short8 ah = *(const short8*)p;
      short8 al = *(const short8*)(p + 5120);
      int wb = ((w*4 + ks)*64 + lane)*8;
      mfma3(acc4, ah, al, *(const short8*)(WPh + wb), *(const short8*)(WPl + wb));
    }
    float hw = (w < 2) ? segw[w*16 + mr] : disw[(w-2)*16 + mr];
    float bb = bias2c[w*16 + mr];
    float* shead = (float*)(sbuf + 21760);   // [4][16][17]
#pragma unroll
    for (int r = 0; r < 4; ++r)
      shead[(w*16 + q*4 + r)*17 + mr] = lrelu(acc4[r] + bb) * hw;
  }
  __syncthreads();
  {
    float* shead = (float*)(sbuf + 21760);
    if (tid < 16) {
      float a = 0.f;
#pragma unroll
      for (int i = 0; i < 16; ++i) a += shead[(tid)*17 + i] + shead[(16 + tid)*17 + i];
      osegp[m0 + tid] = a + segb[0];
    } else if (tid < 32) {
      int r2 = tid - 16;
      float a = 0.f;
#pragma unroll
      for (int i = 0; i < 16; ++i) a += shead[(32 + r2)*17 + i] + shead[(48 + r2)*17 + i];
      odisp[m0 + r2] = a + disb[0];
    }
  }
}

// ---------------- kp: tiny gated keypoint MLP (1 block; g complete via
// kernel-boundary release, no device fence needed) ------------------------------
__global__ void k_kp(const float* __restrict__ g,
                     const float* __restrict__ l1w, const float* __restrict__ l1b,
                     const float* __restrict__ l2w, const float* __restrict__ l2b,
                     const float* __restrict__ l3w, const float* __restrict__ l3b,
                     float* __restrict__ o_kp) {
  __shared__ float sg[128], s1[90], s2[64];
  int tid = threadIdx.x;
  if (tid < 128) sg[tid] = g[tid];
  __syncthreads();
  if (tid < 90) {
    float a = l1b[tid];
    for (int i = 0; i < 128; ++i) a += sg[i]*l1w[tid*128+i];
    s1[tid] = lrelu(a);
  }
  __syncthreads();
  if (tid < 64) {
    float a = l2b[tid];
    for (int i = 0; i < 90; ++i) a += s1[i]*l2w[tid*90+i];
    s2[tid] = lrelu(a);
  }
  __syncthreads();
  if (tid < 24) {
    float a = l3b[tid];
    for (int i = 0; i < 64; ++i) a += s2[i]*l3w[tid*64+i];
    o_kp[tid] = a;
  }
}

extern "C" void kernel_launch(void* const* d_in, const int* in_sizes, int n_in,
                              void* d_out, int out_size, void* d_ws, size_t ws_size,
                              hipStream_t stream) {
  const float* seg      = (const float*)d_in[0];
  const float* img      = (const float*)d_in[1];
  const float* cloud    = (const float*)d_in[2];
  const float* tvec     = (const float*)d_in[3];
  const int*   choose   = (const int*)d_in[4];
  const float* pconv1_w = (const float*)d_in[5];
  const float* pconv1_b = (const float*)d_in[6];
  const float* pconv2_w = (const float*)d_in[7];
  const float* pconv2_b = (const float*)d_in[8];
  const float* conv1_w  = (const float*)d_in[9];
  const float* conv1_b  = (const float*)d_in[10];
  const float* conv2_w  = (const float*)d_in[11];
  const float* conv2_b  = (const float*)d_in[12];
  const float* psconv1_w= (const float*)d_in[13];
  const float* psconv1_b= (const float*)d_in[14];
  const float* psconv2_w= (const float*)d_in[15];
  const float* psconv2_b= (const float*)d_in[16];
  const float* final_w  = (const float*)d_in[17];
  const float* final_b  = (const float*)d_in[18];
  const float* seg1_w   = (const float*)d_in[19];
  const float* seg1_b   = (const float*)d_in[20];
  const float* seg2_w   = (const float*)d_in[21];
  const float* seg2_b   = (const float*)d_in[22];
  const float* seg3_w   = (const float*)d_in[23];
  const float* seg3_b   = (const float*)d_in[24];
  const float* dis1_w   = (const float*)d_in[25];
  const float* dis1_b   = (const float*)d_in[26];
  const float* dis2_w   = (const float*)d_in[27];
  const float* dis2_b   = (const float*)d_in[28];
  const float* dis3_w   = (const float*)d_in[29];
  const float* dis3_b   = (const float*)d_in[30];
  const float* lin1_w   = (const float*)d_in[31];
  const float* lin1_b   = (const float*)d_in[32];
  const float* lin2_w   = (const float*)d_in[33];
  const float* lin2_b   = (const float*)d_in[34];
  const float* lin3_w   = (const float*)d_in[35];
  const float* lin3_b   = (const float*)d_in[36];

  float* out = (float*)d_out;
  float* ws  = (float*)d_ws;

  // workspace layout (float offsets)
  float* c4     = ws + 0;          // 32768
  float* feat   = ws + 32768;      // 262144
  unsigned short* feat_h = (unsigned short*)(ws + 294912);   // 131072 f
  unsigned short* feat_l = (unsigned short*)(ws + 425984);   // 131072 f
  float* pf     = ws + 557056;     // 1048576
  float* Yf     = ws + 1605632;    // 1048576
  float* Yfp    = ws + 2654208;    // 1048576
  int*   idx    = (int*)(ws + 3702784);   // 262144
  float* wsm    = ws + 3964928;    // 262144
  float* soa    = ws + 4227072;    // 32768 (cx|cy|cz|cw, 8192 each)
  unsigned short* Wh    = (unsigned short*)(ws + 9732096);   // 97280 f
  unsigned short* Wl    = (unsigned short*)(ws + 9829376);   // 97280 f
  float* biasc  = ws + 9926656;    // 128
  float* bias2c = ws + 9926784;    // 64
  float* g      = ws + 9926848;    // 129 (g[128] spare)

  float* o_kp   = out;             // 24
  float* o_disp = out + 24;        // 8192
  float* o_dc   = out + 8216;      // 8192
  float* o_segp = out + 16408;     // 8192

  k_prep<<<(PREP_TOTAL + 255)/256, 256, 0, stream>>>(
      cloud, choose, img, seg1_w, dis1_w, seg1_b, dis1_b,
      seg2_w, dis2_w, seg2_b, dis2_b,
      pconv2_w, conv1_w, conv2_w, psconv1_w, psconv2_w, final_w,
      c4, soa, g, biasc, bias2c, feat, feat_h, feat_l, Wh, Wl);

  k_mega<<<MEGA_GRID, 256, 0, stream>>>(
      (const float4*)c4, soa, idx, wsm, cloud, tvec, o_dc,
      pconv1_w, pconv1_b, pconv2_b, psconv1_b, psconv2_b,
      feat_h, feat_l, conv1_b, conv2_b, Wh, Wl, pf, Yfp, Yf);

  k_tail<<<512, 512, 0, stream>>>(
      Yf, Yfp, feat, pf, idx, wsm, Wh, Wl,
      final_b, biasc, bias2c, seg3_w, seg3_b, dis3_w, dis3_b,
      o_dc, seg, g,
      o_segp, o_disp);

  k_kp<<<1, 128, 0, stream>>>(g, lin1_w, lin1_b, lin2_w, lin2_b,
                              lin3_w, lin3_b, o_kp);

  (void)in_sizes; (void)n_in; (void)out_size; (void)ws_size;
}

// Round 7
// 222.727 us; speedup vs baseline: 1.0558x; 1.0558x over previous
//
#include <hip/hip_runtime.h>
#include <math.h>

#define NPT 8192
#define HWIMG 19200
#define KCAP 128

using short8 = __attribute__((ext_vector_type(8))) short;
using short4v = __attribute__((ext_vector_type(4))) short;
using f32x4  = __attribute__((ext_vector_type(4))) float;
using f32x2  = __attribute__((ext_vector_type(2))) float;

__device__ __forceinline__ float lrelu(float x) { return x > 0.f ? x : 0.01f * x; }
__device__ __forceinline__ unsigned short f2bf(float v) {
  unsigned u = __float_as_uint(v);
  return (unsigned short)((u + 0x7fffu + ((u >> 16) & 1u)) >> 16);
}
__device__ __forceinline__ float bf2f(unsigned short h) {
  return __uint_as_float(((unsigned)h) << 16);
}
__device__ __forceinline__ void split2(float v, unsigned short& h, unsigned short& l) {
  h = f2bf(v);
  l = f2bf(v - bf2f(h));
}
__device__ __forceinline__ void mfma3(f32x4& acc, short8 ah, short8 al, short8 wh, short8 wl) {
  acc = __builtin_amdgcn_mfma_f32_16x16x32_bf16(ah, wh, acc, 0, 0, 0);
  acc = __builtin_amdgcn_mfma_f32_16x16x32_bf16(al, wh, acc, 0, 0, 0);
  acc = __builtin_amdgcn_mfma_f32_16x16x32_bf16(ah, wl, acc, 0, 0, 0);
}

// fragment-sequential swizzle: element (row o, k) of a [N,K] matrix lives at
// chunk ((o/16)*Kc + k/32)*64 + (k/8)%4*16 + o%16, byte-offset k%8.
__device__ __forceinline__ int swz(int o, int k, int Kc) {
  return ((((o >> 4) * Kc + (k >> 5)) << 6) + (((k >> 3) & 3) << 4) + (o & 15)) * 8 + (k & 7);
}

// weight-plane segment offsets (in shorts)
#define OFF_PCONV2  0
#define OFF_CONV1   8192
#define OFF_CONV2   10240
#define OFF_PSCONV1 18432
#define OFF_PSCONV2 51200
#define OFF_FINAL   83968
#define OFF_W3      137216
#define OFF_W2P     186368

// ---------------- prep: everything input-only (c4, feat, weights, biases) ------
#define S_C4    NPT
#define S_G     129
#define S_BIASC 128
#define S_B2C   64
#define S_FEAT  (NPT*32)
#define S_W3    49152
#define S_W2P   8192
#define S_WSPL  OFF_W3
#define PREP_TOTAL (S_C4 + S_G + S_BIASC + S_B2C + S_FEAT + S_W3 + S_W2P + S_WSPL)
__global__ void k_prep(const float* __restrict__ cloud, const int* __restrict__ choose,
                       const float* __restrict__ img,
                       const float* __restrict__ seg1_w, const float* __restrict__ dis1_w,
                       const float* __restrict__ seg1_b, const float* __restrict__ dis1_b,
                       const float* __restrict__ seg2_w, const float* __restrict__ dis2_w,
                       const float* __restrict__ seg2_b, const float* __restrict__ dis2_b,
                       const float* __restrict__ pconv2_w, const float* __restrict__ conv1_w,
                       const float* __restrict__ conv2_w, const float* __restrict__ psconv1_w,
                       const float* __restrict__ psconv2_w, const float* __restrict__ final_w,
                       float* __restrict__ c4, float* __restrict__ soa,
                       float* __restrict__ g,
                       float* __restrict__ biasc, float* __restrict__ bias2c,
                       float* __restrict__ feat,
                       unsigned short* __restrict__ feat_h, unsigned short* __restrict__ feat_l,
                       unsigned short* __restrict__ Wh, unsigned short* __restrict__ Wl) {
  int j = blockIdx.x * blockDim.x + threadIdx.x;
  if (j < S_C4) {
    float x = cloud[j*3+0], y = cloud[j*3+1], z = cloud[j*3+2];
    float4 v; v.x = x; v.y = y; v.z = z; v.w = x*x + y*y + z*z;
    ((float4*)c4)[j] = v;
    soa[j] = x; soa[NPT + j] = y; soa[2*NPT + j] = z; soa[3*NPT + j] = v.w;
    return;
  }
  j -= S_C4;
  if (j < S_G) { g[j] = 0.f; return; }
  j -= S_G;
  if (j < S_BIASC) { biasc[j] = (j < 64) ? seg1_b[j] : dis1_b[j-64]; return; }
  j -= S_BIASC;
  if (j < S_B2C) { bias2c[j] = (j < 32) ? seg2_b[j] : dis2_b[j-32]; return; }
  j -= S_B2C;
  if (j < S_FEAT) {
    int n = j >> 5, ch = j & 31;
    float v = img[ch*HWIMG + choose[n]];
    feat[j] = v;
    unsigned short hh, ll; split2(v, hh, ll);
    int d = swz(n, ch, 1);
    feat_h[d] = hh; feat_l[d] = ll;
    return;
  }
  j -= S_FEAT;
  if (j < S_W3) {                          // conv3 weight transpose + split
    int h = j / 24576, r = j - h*24576, o = r / 384, k = r - o*384;
    int t = k >> 7, c = k & 127;
    float v = (h ? dis1_w : seg1_w)[o*384 + c*3 + t];
    unsigned short hh, ll; split2(v, hh, ll);
    int d = OFF_W3 + swz(h*64 + o, k, 12);
    Wh[d] = hh; Wl[d] = ll;
    return;
  }
  j -= S_W3;
  if (j < S_W2P) {                         // W2p block-diagonal + split
    int o = j >> 7, c = j & 127;
    float v = 0.f;
    if (o < 32) { if (c < 64) v = seg2_w[o*64 + c]; }
    else        { if (c >= 64) v = dis2_w[(o-32)*64 + (c-64)]; }
    unsigned short hh, ll; split2(v, hh, ll);
    int d = OFF_W2P + swz(o, c, 4);
    Wh[d] = hh; Wl[d] = ll;
    return;
  }
  j -= S_W2P;
  if (j < S_WSPL) {                        // weight split (swizzled)
    float v; int d;
    if (j < OFF_CONV1) {
      int o = j >> 6, k = j & 63;
      v = pconv2_w[j]; d = OFF_PCONV2 + swz(o, k, 2);
    } else if (j < OFF_CONV2) {
      int jj = j - OFF_CONV1, o = jj >> 5, k = jj & 31;
      v = conv1_w[jj]; d = OFF_CONV1 + swz(o, k, 1);
    } else if (j < OFF_PSCONV1) {
      int jj = j - OFF_CONV2, o = jj >> 6, k = jj & 63;
      v = conv2_w[jj]; d = OFF_CONV2 + swz(o, k, 2);
    } else if (j < OFF_PSCONV2) {
      int jj = j - OFF_PSCONV1, o = jj >> 7, k = jj & 127;
      v = psconv1_w[jj]; d = OFF_PSCONV1 + swz(o, k, 4);
    } else if (j < OFF_FINAL) {
      int jj = j - OFF_PSCONV2, o = jj >> 8, k = jj & 255;
      v = psconv2_w[jj]; d = OFF_PSCONV2 + swz(o, k, 8);
    } else {
      int jj = j - OFF_FINAL, o = jj / 416, k = jj - o*416;
      v = final_w[jj]; d = OFF_FINAL + swz(o, k, 13);
    }
    unsigned short hh, ll; split2(v, hh, ll);
    Wh[d] = hh; Wl[d] = ll;
  }
}

// ---------------- bitonic helpers ---------------------------------------------
__device__ __forceinline__ unsigned bsort32u(unsigned key, int lane) {
#pragma unroll
  for (int k = 2; k <= 64; k <<= 1) {
#pragma unroll
    for (int j = k >> 1; j > 0; j >>= 1) {
      unsigned o = __shfl_xor(key, j, 64);
      bool keepmin = (((lane & j) == 0) == ((lane & k) == 0));
      key = ((o < key) == keepmin) ? o : key;
    }
  }
  return key;
}
__device__ __forceinline__ unsigned long long bsort64(unsigned long long key, int lane) {
#pragma unroll
  for (int k = 2; k <= 64; k <<= 1) {
#pragma unroll
    for (int j = k >> 1; j > 0; j >>= 1) {
      unsigned long long o = __shfl_xor(key, j, 64);
      bool keepmin = (((lane & j) == 0) == ((lane & k) == 0));
      bool omin = o < key;
      key = (omin == keepmin) ? o : key;
    }
  }
  return key;
}
__device__ __forceinline__ unsigned long long bmerge64(unsigned long long key, int lane) {
#pragma unroll
  for (int j = 32; j > 0; j >>= 1) {
    unsigned long long o = __shfl_xor(key, j, 64);
    bool keepmin = ((lane & j) == 0);
    bool omin = o < key;
    key = (omin == keepmin) ? o : key;
  }
  return key;
}

// ---------------- mega: knn (0..1023, 8 q/blk) | dc (1024) | chains (1025..2048)
// LDS: knn needs 8256 B (smin overlaid with sd/sj), chain needs 16384 B
#define MEGA_GRID 2049
__global__ __launch_bounds__(256) void k_mega(const float4* __restrict__ c4,
                                              const float* __restrict__ soa,
                                              int* __restrict__ idxo, float* __restrict__ wo,
                                              const float* __restrict__ cloud,
                                              const float* __restrict__ tvec,
                                              float* __restrict__ dc,
                                              const float* __restrict__ pconv1_w, const float* __restrict__ pconv1_b,
                                              const float* __restrict__ pconv2_b, const float* __restrict__ psconv1_b,
                                              const float* __restrict__ psconv2_b,
                                              const unsigned short* __restrict__ feat_h,
                                              const unsigned short* __restrict__ feat_l,
                                              const float* __restrict__ conv1_b, const float* __restrict__ conv2_b,
                                              const unsigned short* __restrict__ Wh,
                                              const unsigned short* __restrict__ Wl,
                                              float* __restrict__ pf, float* __restrict__ Yfp,
                                              float* __restrict__ Yf) {
  __shared__ __align__(16) char smem[16384];
  int tid = threadIdx.x, lane = tid & 63, w = tid >> 6;
  int mr = lane & 15, q = lane >> 4;
  if (blockIdx.x > 1024) {
    unsigned short* sh_h = (unsigned short*)smem;            // [0,4096) shorts: A @0..2048, B @2048..4096
    unsigned short* sh_l = (unsigned short*)(smem + 8192);
    int cb = blockIdx.x - 1025;
    if (cb < 512) {
      int m0 = cb * 16;
      // stage 1: pconv1 (K=3) directly in A-frag ownership
      float4 cp = c4[m0 + mr];
      short8 ah0, al0, ah1, al1;
#pragma unroll
      for (int j = 0; j < 8; ++j) {
        int c0 = q*8 + j, c1 = 32 + q*8 + j;
        float v0 = lrelu(fmaf(cp.x, pconv1_w[c0*3+0], fmaf(cp.y, pconv1_w[c0*3+1],
                          fmaf(cp.z, pconv1_w[c0*3+2], pconv1_b[c0]))));
        float v1 = lrelu(fmaf(cp.x, pconv1_w[c1*3+0], fmaf(cp.y, pconv1_w[c1*3+1],
                          fmaf(cp.z, pconv1_w[c1*3+2], pconv1_b[c1]))));
        unsigned short hh, ll;
        split2(v0, hh, ll); ah0[j] = (short)hh; al0[j] = (short)ll;
        split2(v1, hh, ll); ah1[j] = (short)hh; al1[j] = (short)ll;
      }
      // stage 2: pconv2 (K=64, N=128) -> region A
      f32x4 acc[2];
#pragma unroll
      for (int t = 0; t < 2; ++t) { f32x4 z = {0.f,0.f,0.f,0.f}; acc[t] = z; }
      const unsigned short* W2h = Wh + OFF_PCONV2;
      const unsigned short* W2l = Wl + OFF_PCONV2;
#pragma unroll
      for (int tt = 0; tt < 2; ++tt) {
        int t1 = 2*w + tt;
        int w0 = ((t1*2 + 0)*64 + lane)*8, w1 = ((t1*2 + 1)*64 + lane)*8;
        mfma3(acc[tt], ah0, al0, *(const short8*)(W2h + w0), *(const short8*)(W2l + w0));
        mfma3(acc[tt], ah1, al1, *(const short8*)(W2h + w1), *(const short8*)(W2l + w1));
      }
#pragma unroll
      for (int tt = 0; tt < 2; ++tt) {
        int t1 = 2*w + tt, n = t1*16 + mr;
        float b = pconv2_b[n];
        int ks2 = t1 >> 1, q2 = (t1 & 1)*2 + (mr >> 3), jd = mr & 7;
#pragma unroll
        for (int r = 0; r < 4; ++r) {
          int row = q*4 + r;
          float v = acc[tt][r] + b;
          pf[(size_t)(m0+row)*128 + n] = v;
          unsigned short hh, ll; split2(v, hh, ll);
          int p = ((ks2*16 + row)*4 + q2)*8 + jd;
          sh_h[p] = hh; sh_l[p] = ll;
        }
      }
      __syncthreads();
      // stages 3+4: psconv1/psconv2 in two 128-col halves (acc3 persists)
      f32x4 acc3[2];
#pragma unroll
      for (int t = 0; t < 2; ++t) { f32x4 z = {0.f,0.f,0.f,0.f}; acc3[t] = z; }
      const unsigned short* W3h = Wh + OFF_PSCONV1;
      const unsigned short* W3l = Wl + OFF_PSCONV1;
      const unsigned short* W4h = Wh + OFF_PSCONV2;
      const unsigned short* W4l = Wl + OFF_PSCONV2;
#pragma unroll
      for (int h = 0; h < 2; ++h) {
        f32x4 acc2[2];
#pragma unroll
        for (int t = 0; t < 2; ++t) { f32x4 z = {0.f,0.f,0.f,0.f}; acc2[t] = z; }
#pragma unroll
        for (int ks = 0; ks < 4; ++ks) {
          int ap = ((ks*16 + mr)*4 + q)*8;
          short8 ah = *(const short8*)&sh_h[ap];
          short8 al = *(const short8*)&sh_l[ap];
#pragma unroll
          for (int tt = 0; tt < 2; ++tt) {
            int ts = h*8 + 2*w + tt;
            int wb = ((ts*4 + ks)*64 + lane)*8;
            mfma3(acc2[tt], ah, al, *(const short8*)(W3h + wb), *(const short8*)(W3l + wb));
          }
        }
#pragma unroll
        for (int tt = 0; tt < 2; ++tt) {
          int tl = 2*w + tt;
          int n = h*128 + tl*16 + mr;
          float b = psconv1_b[n];
          int ks3 = tl >> 1, q3 = (tl & 1)*2 + (mr >> 3), jd = mr & 7;
#pragma unroll
          for (int r = 0; r < 4; ++r) {
            int row = q*4 + r;
            float v = lrelu(acc2[tt][r] + b);
            unsigned short hh, ll; split2(v, hh, ll);
            int p = 2048 + ((ks3*16 + row)*4 + q3)*8 + jd;
            sh_h[p] = hh; sh_l[p] = ll;
          }
        }
        __syncthreads();
#pragma unroll
        for (int ks = 0; ks < 4; ++ks) {
          int ap = 2048 + ((ks*16 + mr)*4 + q)*8;
          short8 ah = *(const short8*)&sh_h[ap];
          short8 al = *(const short8*)&sh_l[ap];
#pragma unroll
          for (int tt = 0; tt < 2; ++tt) {
            int wb = (((2*w+tt)*8 + h*4 + ks)*64 + lane)*8;
            mfma3(acc3[tt], ah, al, *(const short8*)(W4h + wb), *(const short8*)(W4l + wb));
          }
        }
        __syncthreads();
      }
#pragma unroll
      for (int tt = 0; tt < 2; ++tt) {
        int n = (2*w+tt)*16 + mr;
        float b = psconv2_b[n];
#pragma unroll
        for (int r = 0; r < 4; ++r)
          Yfp[(size_t)(m0 + q*4 + r)*128 + n] = acc3[tt][r] + b;
      }
    } else {
      int m0 = (cb - 512) * 16;
      int ab = ((m0 >> 4)*64 + lane)*8;
      short8 ah = *(const short8*)(feat_h + ab);
      short8 al = *(const short8*)(feat_l + ab);
      f32x4 acc = {0.f,0.f,0.f,0.f};
      const unsigned short* W1h = Wh + OFF_CONV1;
      const unsigned short* W1l = Wl + OFF_CONV1;
      {
        int wb = (w*64 + lane)*8;
        mfma3(acc, ah, al, *(const short8*)(W1h + wb), *(const short8*)(W1l + wb));
      }
      {
        int n = w*16 + mr;
        float b = conv1_b[n];
        int ks2 = n >> 5, q2 = (n >> 3) & 3, jd = mr & 7;
#pragma unroll
        for (int r = 0; r < 4; ++r) {
          int row = q*4 + r;
          float v = lrelu(acc[r] + b);
          unsigned short hh, ll; split2(v, hh, ll);
          int p = ((ks2*16 + row)*4 + q2)*8 + jd;
          sh_h[p] = hh; sh_l[p] = ll;
        }
      }
      __syncthreads();
      f32x4 acc2[2];
#pragma unroll
      for (int t = 0; t < 2; ++t) { f32x4 z = {0.f,0.f,0.f,0.f}; acc2[t] = z; }
      const unsigned short* W2h = Wh + OFF_CONV2;
      const unsigned short* W2l = Wl + OFF_CONV2;
#pragma unroll
      for (int ks = 0; ks < 2; ++ks) {
        int ap = ((ks*16 + mr)*4 + q)*8;
        short8 a2 = *(const short8*)&sh_h[ap];
        short8 a2l = *(const short8*)&sh_l[ap];
#pragma unroll
        for (int tt = 0; tt < 2; ++tt) {
          int wb = (((2*w+tt)*2 + ks)*64 + lane)*8;
          mfma3(acc2[tt], a2, a2l, *(const short8*)(W2h + wb), *(const short8*)(W2l + wb));
        }
      }
#pragma unroll
      for (int tt = 0; tt < 2; ++tt) {
        int n = (2*w+tt)*16 + mr;
        float b = conv2_b[n];
#pragma unroll
        for (int r = 0; r < 4; ++r)
          Yf[(size_t)(m0 + q*4 + r)*128 + n] = acc2[tt][r] + b;
      }
    }
    return;
  }
  if (blockIdx.x == 1024) {
    float* sred = (float*)smem;
    float tx = tvec[0], ty = tvec[1], tz = tvec[2];
    float v[32];
    float m = -INFINITY;
#pragma unroll
    for (int i2 = 0; i2 < 32; ++i2) {
      int n = i2*256 + tid;
      float ax = cloud[n*3+0] + tx, ay = cloud[n*3+1] + ty, az = cloud[n*3+2] + tz;
      v[i2] = sqrtf(ax*ax + ay*ay + az*az);
      m = fmaxf(m, v[i2]);
    }
#pragma unroll
    for (int o = 1; o < 64; o <<= 1) m = fmaxf(m, __shfl_xor(m, o, 64));
    if (lane == 0) sred[w] = m;
    __syncthreads();
    m = fmaxf(fmaxf(sred[0], sred[1]), fmaxf(sred[2], sred[3]));
    __syncthreads();
    float s = 0.f;
#pragma unroll
    for (int i2 = 0; i2 < 32; ++i2) { v[i2] = expf(v[i2] - m); s += v[i2]; }
#pragma unroll
    for (int o = 1; o < 64; o <<= 1) s += __shfl_xor(s, o, 64);
    if (lane == 0) sred[w] = s;
    __syncthreads();
    s = sred[0] + sred[1] + sred[2] + sred[3];
#pragma unroll
    for (int i2 = 0; i2 < 32; ++i2) dc[i2*256 + tid] = v[i2] / s;
    return;
  }
  // knn: 8 queries/block, SoA packed-fp32 scan. smin (pass 1) overlays sd/sj
  // (pass 2) -- disjoint in time, barrier-separated.
  float (*smin)[256] = (float(*)[256])smem;                 // 8192 B (pass 1)
  float (*sd)[KCAP] = (float(*)[KCAP])smem;                 // 4096 B (pass 2)
  int   (*sj)[KCAP] = (int(*)[KCAP])(smem + 4096);          // 4096 B (pass 2)
  float* sTv = (float*)(smem + 8192);                       // 32 B
  int*   scnt = (int*)(smem + 8224);                        // 32 B
  const float* cx = soa;
  const float* cy = soa + NPT;
  const float* cz = soa + 2*NPT;
  const float* cw = soa + 3*NPT;
  int q0 = blockIdx.x * 8;
  float4 P[8];
#pragma unroll
  for (int i = 0; i < 8; ++i) P[i] = c4[q0 + i];
  f32x2 QX[8], QY[8], QZ[8], QW[8];
#pragma unroll
  for (int i = 0; i < 8; ++i) {
    QX[i][0] = QX[i][1] = -2.f*P[i].x;
    QY[i][0] = QY[i][1] = -2.f*P[i].y;
    QZ[i][0] = QZ[i][1] = -2.f*P[i].z;
    QW[i][0] = QW[i][1] = P[i].w;
  }
#define PDOT(QXI,QYI,QZI,QWI) \
  __builtin_elementwise_fma(X, QXI, __builtin_elementwise_fma(Yv, QYI, \
    __builtin_elementwise_fma(Z, QZI, Wv + QWI)))
  f32x2 inf2 = {INFINITY, INFINITY};
  f32x2 mv[8];
#pragma unroll
  for (int i = 0; i < 8; ++i) mv[i] = inf2;
  for (int t = 0; t < 16; ++t) {
    int j = t*512 + tid*2;
    f32x2 X  = *(const f32x2*)&cx[j];
    f32x2 Yv = *(const f32x2*)&cy[j];
    f32x2 Z  = *(const f32x2*)&cz[j];
    f32x2 Wv = *(const f32x2*)&cw[j];
#pragma unroll
    for (int i = 0; i < 8; ++i)
      mv[i] = __builtin_elementwise_min(mv[i], PDOT(QX[i],QY[i],QZ[i],QW[i]));
  }
#pragma unroll
  for (int i = 0; i < 8; ++i) smin[i][tid] = fminf(mv[i][0], mv[i][1]);
  if (tid < 8) scnt[tid] = 0;
  __syncthreads();
#pragma unroll
  for (int u = 0; u < 2; ++u) {
    int qq = w*2 + u;
    float4 vv = *(const float4*)&smin[qq][lane*4];
    float m4 = fmaxf(fminf(fminf(vv.x, vv.y), fminf(vv.z, vv.w)), 0.f);
    unsigned key = bsort32u(__float_as_uint(m4), lane);
    float T = __uint_as_float(__shfl(key, 31, 64));
    if (lane == 0) sTv[qq] = T * (1.f + 2e-5f) + 4e-5f;
  }
  __syncthreads();   // smin reads done; sd/sj overlay now writable
  float Tq[8];
#pragma unroll
  for (int i = 0; i < 8; ++i) Tq[i] = sTv[i];
#define APPEND8(Q, PQ, XX, YY, ZZ, J) { \
    float dx_ = (PQ).x-(XX), dy_ = (PQ).y-(YY), dz_ = (PQ).z-(ZZ); \
    float de_ = dx_*dx_ + dy_*dy_ + dz_*dz_; \
    int p_ = atomicAdd(&scnt[Q],1); if (p_ < KCAP) { sd[Q][p_] = de_; sj[Q][p_] = (J); } }
  for (int t = 0; t < 16; ++t) {
    int j = t*512 + tid*2;
    f32x2 X  = *(const f32x2*)&cx[j];
    f32x2 Yv = *(const f32x2*)&cy[j];
    f32x2 Z  = *(const f32x2*)&cz[j];
    f32x2 Wv = *(const f32x2*)&cw[j];
#pragma unroll
    for (int i = 0; i < 8; ++i) {
      f32x2 d = PDOT(QX[i],QY[i],QZ[i],QW[i]);
      if (d[0] <= Tq[i]) APPEND8(i, P[i], X[0], Yv[0], Z[0], j);
      if (d[1] <= Tq[i]) APPEND8(i, P[i], X[1], Yv[1], Z[1], j+1);
    }
  }
  __syncthreads();
#pragma unroll
  for (int u = 0; u < 2; ++u) {
    int qq = w*2 + u;
    int M = scnt[qq]; if (M > KCAP) M = KCAP;
    unsigned long long key = (lane < M)
        ? (((unsigned long long)__float_as_uint(sd[qq][lane]) << 32) | (unsigned)sj[qq][lane])
        : ~0ull;
    key = bsort64(key, lane);
    for (int base = 64; base < M; base += 64) {
      unsigned long long nk = (base + lane < M)
          ? (((unsigned long long)__float_as_uint(sd[qq][base+lane]) << 32) | (unsigned)sj[qq][base+lane])
          : ~0ull;
      nk = bsort64(nk, lane);
      nk = __shfl_xor(nk, 63, 64);
      key = key < nk ? key : nk;
      key = bmerge64(key, lane);
    }
    float dsel = __uint_as_float((unsigned)(key >> 32));
    int   jsel = (int)(unsigned)(key & 0xffffffffu);
    float v = -sqrtf(dsel);
    float mx = v;
#pragma unroll
    for (int o = 1; o < 32; o <<= 1) mx = fmaxf(mx, __shfl_xor(mx, o, 64));
    float e = expf(v - mx);
    float s = e;
#pragma unroll
    for (int o = 1; o < 32; o <<= 1) s += __shfl_xor(s, o, 64);
    if (lane < 32) {
      int qd = q0 + qq;
      wo[qd*32 + lane] = e / s;
      idxo[qd*32 + lane] = jsel;
    }
  }
}

// ---------------- tail: pool(18 rows) + final GEMM + conv3 + head + g-partials -
// 512 threads (8 waves), __launch_bounds__(512,4) pins VGPR<=128 so 2 blocks/CU
// (16 waves/CU) is guaranteed -- the R6 build couldn't confirm VGPR<=128 and a
// spill past 128 would have dropped to 1 block/CU. P2 batch is now 2x16 chunks
// (live set ~64 VGPR) so the bound is comfortable, no scratch.
__global__ __launch_bounds__(512, 4) void k_tail(const float* __restrict__ Yf,
                                              const float* __restrict__ Yfp,
                                              const float* __restrict__ feat,
                                              const float* __restrict__ pf,
                                              const int* __restrict__ idx,
                                              const float* __restrict__ wsm,
                                              const unsigned short* __restrict__ Wh,
                                              const unsigned short* __restrict__ Wl,
                                              const float* __restrict__ final_b,
                                              const float* __restrict__ biasc,
                                              const float* __restrict__ bias2c,
                                              const float* __restrict__ segw, const float* __restrict__ segb,
                                              const float* __restrict__ disw, const float* __restrict__ disb,
                                              const float* __restrict__ dcw, const float* __restrict__ segin,
                                              float* __restrict__ g,
                                              float* __restrict__ osegp, float* __restrict__ odisp) {
  __shared__ int sjn[18][32];
  __shared__ float swn[18][32];
  __shared__ __align__(16) char sbuf[37440];
  int tid = threadIdx.x, lane = tid & 63, w = tid >> 6;
  int mr = lane & 15, q = lane >> 4;
  int mt = blockIdx.x, m0 = mt * 16;
  // P1: neighbor lists for 18 rows (halo +-1)
  for (int t = tid; t < 18*32; t += 512) {
    int lr = t >> 5, k = t & 31, gr = m0 - 1 + lr;
    if (gr >= 0 && gr < NPT) { sjn[lr][k] = idx[gr*32+k]; swn[lr][k] = wsm[gr*32+k]; }
    else { sjn[lr][k] = 0; swn[lr][k] = 0.f; }
  }
  __syncthreads();
  // P2: build fin[18][416] split planes in LDS (1872 items of 4 channels).
  // Gather in 2 chunks of 16 rows: 16 loads in flight (issue-early/use-late)
  // with bounded ~64-VGPR live set.
  for (int t = tid; t < 1872; t += 512) {
    int lr, col;
    float4 v4;
    if (t < 1152) {
      lr = t >> 6; int arr = (t >> 5) & 1, cg = t & 31;
      const float* Y = arr ? Yf : Yfp;
      float ax = -INFINITY, ay = -INFINITY, az = -INFINITY, aw = -INFINITY;
#pragma unroll
      for (int half = 0; half < 2; ++half) {
        float4 vv[16];
#pragma unroll
        for (int k = 0; k < 16; ++k)
          vv[k] = *(const float4*)&Y[(size_t)sjn[lr][half*16 + k]*128 + cg*4];
#pragma unroll
        for (int k = 0; k < 16; ++k) {
          float wk = swn[lr][half*16 + k];
          ax = fmaxf(ax, wk*vv[k].x); ay = fmaxf(ay, wk*vv[k].y);
          az = fmaxf(az, wk*vv[k].z); aw = fmaxf(aw, wk*vv[k].w);
        }
      }
      v4.x = lrelu(ax); v4.y = lrelu(ay); v4.z = lrelu(az); v4.w = lrelu(aw);
      col = (arr ? 160 : 0) + cg*4;
    } else if (t < 1728) {
      int u = t - 1152; lr = u >> 5; int cg = u & 31;
      int gr = m0 - 1 + lr;
      int gc = gr < 0 ? 0 : (gr >= NPT ? NPT-1 : gr);
      float4 p4 = *(const float4*)&pf[(size_t)gc*128 + cg*4];
      v4.x = lrelu(p4.x); v4.y = lrelu(p4.y); v4.z = lrelu(p4.z); v4.w = lrelu(p4.w);
      col = 288 + cg*4;
    } else {
      int u = t - 1728; lr = u >> 3; int cg = u & 7;
      int gr = m0 - 1 + lr;
      int gc = gr < 0 ? 0 : (gr >= NPT ? NPT-1 : gr);
      float4 p4 = *(const float4*)&feat[(size_t)gc*32 + cg*4];
      v4.x = lrelu(p4.x); v4.y = lrelu(p4.y); v4.z = lrelu(p4.z); v4.w = lrelu(p4.w);
      col = 128 + cg*4;
    }
    int gr = m0 - 1 + lr;
    if (gr < 0 || gr >= NPT) { v4.x = 0.f; v4.y = 0.f; v4.z = 0.f; v4.w = 0.f; }
    int ks = col >> 5, qq = (col >> 3) & 3, j0 = col & 7;
    char* base = sbuf + (ks*18 + lr)*80 + qq*16 + j0*2;
    short4v hv, lv;
    unsigned short hh, ll;
    split2(v4.x, hh, ll); hv[0] = (short)hh; lv[0] = (short)ll;
    split2(v4.y, hh, ll); hv[1] = (short)hh; lv[1] = (short)ll;
    split2(v4.z, hh, ll); hv[2] = (short)hh; lv[2] = (short)ll;
    split2(v4.w, hh, ll); hv[3] = (short)hh; lv[3] = (short)ll;
    *(short4v*)base = hv;
    *(short4v*)(base + 18720) = lv;
  }
  __syncthreads();
  // P3: final GEMM (K=416); warp w owns n-tile w (16 cols), rows 0..15 (A) and
  // 16..17 clamp (B)
  f32x4 accA = {0.f,0.f,0.f,0.f}, accB = {0.f,0.f,0.f,0.f};
  const unsigned short* WFh = Wh + OFF_FINAL;
  const unsigned short* WFl = Wl + OFF_FINAL;
#pragma unroll
  for (int ks = 0; ks < 13; ++ks) {
    int arB = 16 + mr; if (arB > 17) arB = 17;
    const char* pA = sbuf + (ks*18 + mr)*80 + q*16;
    const char* pB = sbuf + (ks*18 + arB)*80 + q*16;
    short8 ahA = *(const short8*)pA;
    short8 alA = *(const short8*)(pA + 18720);
    short8 ahB = *(const short8*)pB;
    short8 alB = *(const short8*)(pB + 18720);
    int wb = ((w*13 + ks)*64 + lane)*8;
    short8 wh = *(const short8*)(WFh + wb);
    short8 wl = *(const short8*)(WFl + wb);
    mfma3(accA, ahA, alA, wh, wl);
    mfma3(accB, ahB, alB, wh, wl);
  }
  __syncthreads();   // all fin reads done; overlay region now writable
  // P3b: write fused split planes to LDS overlay (zero OOB rows = conv zero-pad)
  {
    int t2 = w, n = t2*16 + mr;
    float b = final_b[n];
    int ksA = t2 >> 1, qq = (t2 & 1)*2 + (mr >> 3), jd = mr & 7;
#pragma unroll
    for (int r = 0; r < 4; ++r) {            // rows 0..15 (tile A)
      int lr = q*4 + r;
      int gr = m0 - 1 + lr;
      float v = accA[r] + b;
      if (gr < 0 || gr >= NPT) v = 0.f;
      unsigned short hh, ll; split2(v, hh, ll);
      char* p = sbuf + (ksA*18 + lr)*80 + qq*16 + jd*2;
      *(unsigned short*)p = hh;
      *(unsigned short*)(p + 5760) = ll;
    }
#pragma unroll
    for (int r = 0; r < 4; ++r) {            // rows 16..17 (tile B, clamped)
      int lr = 16 + q*4 + r;
      if (lr > 17) continue;
      int gr = m0 - 1 + lr;
      float v = accB[r] + b;
      if (gr < 0 || gr >= NPT) v = 0.f;
      unsigned short hh, ll; split2(v, hh, ll);
      char* p = sbuf + (ksA*18 + lr)*80 + qq*16 + jd*2;
      *(unsigned short*)p = hh;
      *(unsigned short*)(p + 5760) = ll;
    }
  }
  __syncthreads();
  // P3c: per-block weighted partial g -> fire-and-forget atomicAdd (no fence)
  if (tid < 256) {
    int ks2 = tid >> 6, q2 = (tid >> 4) & 3, mr2 = tid & 15;
    int lr = mr2 + 1;
    const char* p = sbuf + (ks2*18 + lr)*80 + q2*16;
    short8 oh = *(const short8*)p;
    short8 ol = *(const short8*)(p + 5760);
    int gr = m0 + mr2;
    float wrow = dcw[gr] * segin[gr];
    float* sred = (float*)(sbuf + 26112);
#pragma unroll
    for (int j = 0; j < 8; ++j)
      sred[tid*8 + j] = (bf2f((unsigned short)oh[j]) + bf2f((unsigned short)ol[j])) * wrow;
  }
  __syncthreads();
  if (tid < 128) {
    float* sred = (float*)(sbuf + 26112);
    int ks = tid >> 5, q2 = (tid >> 3) & 3, j = tid & 7;
    float s = 0.f;
#pragma unroll
    for (int mr2 = 0; mr2 < 16; ++mr2) s += sred[((ks << 6) + (q2 << 4) + mr2)*8 + j];
    atomicAdd(&g[tid], s);
  }
  // P4: conv3 (K=384 via taps); warp w owns n-tile w
  f32x4 acc3 = {0.f,0.f,0.f,0.f};
  const unsigned short* W3h = Wh + OFF_W3;
  const unsigned short* W3l = Wl + OFF_W3;
#pragma unroll
  for (int ks = 0; ks < 12; ++ks) {
    int tap = ks >> 2, ksA = ks & 3;
    int ar = mr + tap;                     // local fused row 0..17
    const char* p = sbuf + (ksA*18 + ar)*80 + q*16;
    short8 ah = *(const short8*)p;
    short8 al = *(const short8*)(p + 5760);
    int wb = ((w*12 + ks)*64 + lane)*8;
    mfma3(acc3, ah, al, *(const short8*)(W3h + wb), *(const short8*)(W3l + wb));
  }
  {
    int t2 = w, n = t2*16 + mr;
    float b = biasc[n];
    int ks2 = t2 >> 1, q2 = (t2 & 1)*2 + (mr >> 3), jd = mr & 7;
#pragma unroll
    for (int r = 0; r < 4; ++r) {
      int row = q*4 + r;
      float v = lrelu(acc3[r] + b);
      unsigned short hh, ll; split2(v, hh, ll);
      char* p = sbuf + 11520 + (ks2*16 + row)*80 + q2*16 + jd*2;
      *(unsigned short*)p = hh;
      *(unsigned short*)(p + 5120) = ll;
    }
  }
  __syncthreads();
  // P5: head GEMM (K=128, block-diag seg2|dis2) on warps 0..3 only
  if (w < 4) {
    f32x4 acc4 = {0.f,0.f,0.f,0.f};
    const unsigned short* WPh = Wh + OFF_W2P;
    const unsigned short* WPl = Wl + OFF_W2P;
#pragma unroll
    for (int ks = 0; ks < 4; ++ks) {
      const char* p = sbuf + 11520 + (ks*16 + mr)*80 + q*16;
      short8 ah = *(const short8*)p;
      short8 al = *(const short8*)(p + 5120);
      int wb = ((w*4 + ks)*64 + lane)*8;
      mfma3(acc4, ah, al, *(const short8*)(WPh + wb), *(const short8*)(WPl + wb));
    }
    float hw = (w < 2) ? segw[w*16 + mr] : disw[(w-2)*16 + mr];
    float bb = bias2c[w*16 + mr];
    float* shead = (float*)(sbuf + 21760);   // [4][16][17]
#pragma unroll
    for (int r = 0; r < 4; ++r)
      shead[(w*16 + q*4 + r)*17 + mr] = lrelu(acc4[r] + bb) * hw;
  }
  __syncthreads();
  {
    float* shead = (float*)(sbuf + 21760);
    if (tid < 16) {
      float a = 0.f;
#pragma unroll
      for (int i = 0; i < 16; ++i) a += shead[(tid)*17 + i] + shead[(16 + tid)*17 + i];
      osegp[m0 + tid] = a + segb[0];
    } else if (tid < 32) {
      int r2 = tid - 16;
      float a = 0.f;
#pragma unroll
      for (int i = 0; i < 16; ++i) a += shead[(32 + r2)*17 + i] + shead[(48 + r2)*17 + i];
      odisp[m0 + r2] = a + disb[0];
    }
  }
}

// ---------------- kp: tiny gated keypoint MLP (1 block; g complete via
// kernel-boundary release, no device fence needed) ------------------------------
__global__ void k_kp(const float* __restrict__ g,
                     const float* __restrict__ l1w, const float* __restrict__ l1b,
                     const float* __restrict__ l2w, const float* __restrict__ l2b,
                     const float* __restrict__ l3w, const float* __restrict__ l3b,
                     float* __restrict__ o_kp) {
  __shared__ float sg[128], s1[90], s2[64];
  int tid = threadIdx.x;
  if (tid < 128) sg[tid] = g[tid];
  __syncthreads();
  if (tid < 90) {
    float a = l1b[tid];
    for (int i = 0; i < 128; ++i) a += sg[i]*l1w[tid*128+i];
    s1[tid] = lrelu(a);
  }
  __syncthreads();
  if (tid < 64) {
    float a = l2b[tid];
    for (int i = 0; i < 90; ++i) a += s1[i]*l2w[tid*90+i];
    s2[tid] = lrelu(a);
  }
  __syncthreads();
  if (tid < 24) {
    float a = l3b[tid];
    for (int i = 0; i < 64; ++i) a += s2[i]*l3w[tid*64+i];
    o_kp[tid] = a;
  }
}

extern "C" void kernel_launch(void* const* d_in, const int* in_sizes, int n_in,
                              void* d_out, int out_size, void* d_ws, size_t ws_size,
                              hipStream_t stream) {
  const float* seg      = (const float*)d_in[0];
  const float* img      = (const float*)d_in[1];
  const float* cloud    = (const float*)d_in[2];
  const float* tvec     = (const float*)d_in[3];
  const int*   choose   = (const int*)d_in[4];
  const float* pconv1_w = (const float*)d_in[5];
  const float* pconv1_b = (const float*)d_in[6];
  const float* pconv2_w = (const float*)d_in[7];
  const float* pconv2_b = (const float*)d_in[8];
  const float* conv1_w  = (const float*)d_in[9];
  const float* conv1_b  = (const float*)d_in[10];
  const float* conv2_w  = (const float*)d_in[11];
  const float* conv2_b  = (const float*)d_in[12];
  const float* psconv1_w= (const float*)d_in[13];
  const float* psconv1_b= (const float*)d_in[14];
  const float* psconv2_w= (const float*)d_in[15];
  const float* psconv2_b= (const float*)d_in[16];
  const float* final_w  = (const float*)d_in[17];
  const float* final_b  = (const float*)d_in[18];
  const float* seg1_w   = (const float*)d_in[19];
  const float* seg1_b   = (const float*)d_in[20];
  const float* seg2_w   = (const float*)d_in[21];
  const float* seg2_b   = (const float*)d_in[22];
  const float* seg3_w   = (const float*)d_in[23];
  const float* seg3_b   = (const float*)d_in[24];
  const float* dis1_w   = (const float*)d_in[25];
  const float* dis1_b   = (const float*)d_in[26];
  const float* dis2_w   = (const float*)d_in[27];
  const float* dis2_b   = (const float*)d_in[28];
  const float* dis3_w   = (const float*)d_in[29];
  const float* dis3_b   = (const float*)d_in[30];
  const float* lin1_w   = (const float*)d_in[31];
  const float* lin1_b   = (const float*)d_in[32];
  const float* lin2_w   = (const float*)d_in[33];
  const float* lin2_b   = (const float*)d_in[34];
  const float* lin3_w   = (const float*)d_in[35];
  const float* lin3_b   = (const float*)d_in[36];

  float* out = (float*)d_out;
  float* ws  = (float*)d_ws;

  // workspace layout (float offsets)
  float* c4     = ws + 0;          // 32768
  float* feat   = ws + 32768;      // 262144
  unsigned short* feat_h = (unsigned short*)(ws + 294912);   // 131072 f
  unsigned short* feat_l = (unsigned short*)(ws + 425984);   // 131072 f
  float* pf     = ws + 557056;     // 1048576
  float* Yf     = ws + 1605632;    // 1048576
  float* Yfp    = ws + 2654208;    // 1048576
  int*   idx    = (int*)(ws + 3702784);   // 262144
  float* wsm    = ws + 3964928;    // 262144
  float* soa    = ws + 4227072;    // 32768 (cx|cy|cz|cw, 8192 each)
  unsigned short* Wh    = (unsigned short*)(ws + 9732096);   // 97280 f
  unsigned short* Wl    = (unsigned short*)(ws + 9829376);   // 97280 f
  float* biasc  = ws + 9926656;    // 128
  float* bias2c = ws + 9926784;    // 64
  float* g      = ws + 9926848;    // 129 (g[128] spare)

  float* o_kp   = out;             // 24
  float* o_disp = out + 24;        // 8192
  float* o_dc   = out + 8216;      // 8192
  float* o_segp = out + 16408;     // 8192

  k_prep<<<(PREP_TOTAL + 255)/256, 256, 0, stream>>>(
      cloud, choose, img, seg1_w, dis1_w, seg1_b, dis1_b,
      seg2_w, dis2_w, seg2_b, dis2_b,
      pconv2_w, conv1_w, conv2_w, psconv1_w, psconv2_w, final_w,
      c4, soa, g, biasc, bias2c, feat, feat_h, feat_l, Wh, Wl);

  k_mega<<<MEGA_GRID, 256, 0, stream>>>(
      (const float4*)c4, soa, idx, wsm, cloud, tvec, o_dc,
      pconv1_w, pconv1_b, pconv2_b, psconv1_b, psconv2_b,
      feat_h, feat_l, conv1_b, conv2_b, Wh, Wl, pf, Yfp, Yf);

  k_tail<<<512, 512, 0, stream>>>(
      Yf, Yfp, feat, pf, idx, wsm, Wh, Wl,
      final_b, biasc, bias2c, seg3_w, seg3_b, dis3_w, dis3_b,
      o_dc, seg, g,
      o_segp, o_disp);

  k_kp<<<1, 128, 0, stream>>>(g, lin1_w, lin1_b, lin2_w, lin2_b,
                              lin3_w, lin3_b, o_kp);

  (void)in_sizes; (void)n_in; (void)out_size; (void)ws_size;
}